// Round 1
// baseline (179.436 us; speedup 1.0000x reference)
//
#include <hip/hip_runtime.h>
#include <hip/hip_bf16.h>
#include <math.h>
#include <stdint.h>

#define B_ 2
#define T_ 2048
#define C_ 1024
#define H_ 16
#define D_ 64

typedef __attribute__((ext_vector_type(8))) short bf16x8;
typedef __attribute__((ext_vector_type(4))) float f32x4;

__device__ inline short f2bf(float f) {
  __hip_bfloat16 h = __float2bfloat16(f);
  return *(short*)&h;
}

// async global->LDS, 16B/lane. LDS image = wave-uniform base + lane*16.
__device__ inline void async16(const void* g, void* l) {
  __builtin_amdgcn_global_load_lds(
      (const __attribute__((address_space(1))) uint32_t*)g,
      (__attribute__((address_space(3))) uint32_t*)l, 16, 0, 0);
}

// ---------------------------------------------------------------------------
// Swizzle convention for GEMM operand images (A [M,1024] and B^T [N,1024]):
// chunk p of each 32-k group holds source chunk (p ^ ((row>>1)&3)).
// Fragment reads use chunk (quad ^ ((l16>>1)&3)) -> 2-way banks (free).
// ---------------------------------------------------------------------------

// One prep kernel: blocks [0,512) convert x -> bf16 swizzled (coalesced:
// each pass one full 4KB row per block); [512,1280) transpose w_qkv;
// [1280,1536) transpose w_proj.
__global__ __launch_bounds__(256) void prep(
    const float* __restrict__ X, const float* __restrict__ Wq,
    const float* __restrict__ Wp, short* __restrict__ Xb,
    short* __restrict__ Wqt, short* __restrict__ Wpt) {
  const int tid = threadIdx.x;
  const int blk = blockIdx.x;
  __shared__ short Ts[64][68];

  if (blk < 512) {  // convert_x: 8 rows per block, 1 row (1024 f32) per pass
    const int g = tid >> 3;        // 32-float group in row
    const int sub = tid & 7;       // 4-float slot in group
    const int sc = sub >> 1;       // source chunk 0..3
    const int e4 = (sub & 1) * 4;
#pragma unroll
    for (int pass = 0; pass < 8; ++pass) {
      const int m = blk * 8 + pass;
      float4 v = *(const float4*)(X + (size_t)m * C_ + tid * 4);
      const int xv = (m >> 1) & 3;
      short o[4] = {f2bf(v.x), f2bf(v.y), f2bf(v.z), f2bf(v.w)};
      *(uint2*)(Xb + (size_t)m * C_ + g * 32 + ((sc ^ xv) << 3) + e4) =
          *(uint2*)o;
    }
    return;
  }

  const float* W;
  short* Wt;
  int N, n0, k0;
  if (blk < 1280) {
    int i = blk - 512;
    W = Wq; Wt = Wqt; N = 3 * C_;
    n0 = (i % 48) * 64; k0 = (i / 48) * 64;
  } else {
    int i = blk - 1280;
    W = Wp; Wt = Wpt; N = C_;
    n0 = (i & 15) * 64; k0 = (i >> 4) * 64;
  }
  {
    int r = tid >> 2, c0 = (tid & 3) * 16;
    const float* src = W + (size_t)(k0 + r) * N + n0 + c0;
#pragma unroll
    for (int u = 0; u < 16; u += 4) {
      float4 v = *(const float4*)(src + u);
      Ts[r][c0 + u + 0] = f2bf(v.x);
      Ts[r][c0 + u + 1] = f2bf(v.y);
      Ts[r][c0 + u + 2] = f2bf(v.z);
      Ts[r][c0 + u + 3] = f2bf(v.w);
    }
  }
  __syncthreads();
  // write: 8 lanes cover one output row's 64 k (128 B contiguous, coalesced)
#pragma unroll
  for (int p = 0; p < 2; ++p) {
    int n = (tid >> 3) + p * 32;
    int kc = tid & 7;
    int xv = ((n0 + n) >> 1) & 3;
    int ka = kc * 8;
    int dk = (ka & ~31) | ((((ka >> 3) & 3) ^ xv) << 3);
    short tmp[8];
#pragma unroll
    for (int u = 0; u < 8; ++u) tmp[u] = Ts[ka + u][n];
    *(uint4*)(Wt + (size_t)(n0 + n) * 1024 + k0 + dk) = *(uint4*)tmp;
  }
}

// ---------------------------------------------------------------------------
// bf16 MFMA GEMM, 128xBN tile, BK=64 staged as TWO consecutive BK=32 images
// in the round-5 conflict-free swizzled [row][32k] layout.
// QKV=true (BN=128): scatter epilogue -> attention-tiled Q/K/V:
//   Q,K: [bh][t>>6][d>>3][t&63][d&7]   (per-bh stride 131072 shorts)
//   V:   [bh][t>>6][(t&63)>>3][d][t&7].
// Q is pre-scaled by (1/sqrt(D))*log2(e) so attention can use raw v_exp_f32
// (exp2) with no per-score multiply.
// ---------------------------------------------------------------------------
template <int N, int BN, bool QKV>
__global__ __launch_bounds__(256) void gemm_mfma(
    const short* __restrict__ A, const short* __restrict__ Bt,
    const float* __restrict__ bias, short* __restrict__ Qp,
    short* __restrict__ Kp, short* __restrict__ Vp, float* __restrict__ Cout) {
  constexpr int NJ = BN / 32;      // n-tiles per wave
  constexpr int BI = BN * 32;      // B image size (shorts)
  const int tid = threadIdx.x;
  const int wave = tid >> 6, lane = tid & 63;
  const int quad = lane >> 4, l16 = lane & 15;
  const int wm = wave >> 1, wn = wave & 1;
  const int m0 = blockIdx.y * 128, n0 = blockIdx.x * BN;

  __shared__ short As[2][4096];    // two 32-k images, [row][32k] swizzled
  __shared__ short Bs[2][BI];

  const int srow = tid >> 2, skc = tid & 3;
  const size_t arow0 = (size_t)(m0 + srow) * 1024 + skc * 8;
  const size_t brow0 = (size_t)(n0 + srow) * 1024 + skc * 8;

  f32x4 acc[4][NJ] = {};

  const int xi = quad ^ ((l16 >> 1) & 3);  // de-swizzle chunk select
  int aoff[4], boff[NJ];
#pragma unroll
  for (int i = 0; i < 4; ++i) aoff[i] = (wm * 64 + i * 16 + l16) * 32 + xi * 8;
#pragma unroll
  for (int j = 0; j < NJ; ++j)
    boff[j] = (wn * (BN / 2) + j * 16 + l16) * 32 + xi * 8;

  for (int k0 = 0; k0 < 1024; k0 += 64) {
    __syncthreads();  // prior reads done before overwrite
#pragma unroll
    for (int f = 0; f < 2; ++f) {
      const int kf = k0 + f * 32;
      async16(A + arow0 + kf, &As[f][tid * 8]);
      async16(A + arow0 + (size_t)64 * 1024 + kf, &As[f][2048 + tid * 8]);
      async16(Bt + brow0 + kf, &Bs[f][tid * 8]);
      if (BN == 128)
        async16(Bt + brow0 + (size_t)64 * 1024 + kf, &Bs[f][2048 + tid * 8]);
    }
    __syncthreads();  // staging visible (vmcnt drained by barrier)

#pragma unroll
    for (int f = 0; f < 2; ++f) {
      bf16x8 af[4], bfr[NJ];
#pragma unroll
      for (int i = 0; i < 4; ++i) af[i] = *(const bf16x8*)&As[f][aoff[i]];
#pragma unroll
      for (int j = 0; j < NJ; ++j) bfr[j] = *(const bf16x8*)&Bs[f][boff[j]];
#pragma unroll
      for (int i = 0; i < 4; ++i)
#pragma unroll
        for (int j = 0; j < NJ; ++j)
          acc[i][j] = __builtin_amdgcn_mfma_f32_16x16x32_bf16(
              af[i], bfr[j], acc[i][j], 0, 0, 0);
    }
  }

  float bj[NJ];
#pragma unroll
  for (int j = 0; j < NJ; ++j) bj[j] = bias[n0 + wn * (BN / 2) + j * 16 + l16];

  if (QKV) {
#pragma unroll
    for (int i = 0; i < 4; ++i) {
#pragma unroll
      for (int reg = 0; reg < 4; ++reg) {
        int m = m0 + wm * 64 + i * 16 + quad * 4 + reg;
        int b = m >> 11, t = m & (T_ - 1);
#pragma unroll
        for (int j = 0; j < NJ; ++j) {
          int n = n0 + wn * (BN / 2) + j * 16 + l16;
          float v = acc[i][j][reg] + bj[j];
          int sel = n >> 10, cc = n & (C_ - 1);
          int hh = cc >> 6, d = cc & 63;
          size_t base = (size_t)(b * H_ + hh) * 131072 + (size_t)(t >> 6) * 4096;
          if (sel == 0) {
            // 0.125 * log2(e) = 0.18033688011
            Qp[base + (d >> 3) * 512 + (t & 63) * 8 + (d & 7)] =
                f2bf(v * 0.18033688011112042f);
          } else if (sel == 1) {
            Kp[base + (d >> 3) * 512 + (t & 63) * 8 + (d & 7)] = f2bf(v);
          } else {
            Vp[base + ((t & 63) >> 3) * 512 + d * 8 + (t & 7)] = f2bf(v);
          }
        }
      }
    }
  } else {
#pragma unroll
    for (int i = 0; i < 4; ++i) {
#pragma unroll
      for (int reg = 0; reg < 4; ++reg) {
        int m = m0 + wm * 64 + i * 16 + quad * 4 + reg;
#pragma unroll
        for (int j = 0; j < NJ; ++j) {
          int n = n0 + wn * (BN / 2) + j * 16 + l16;
          Cout[(size_t)m * N + n] = acc[i][j][reg] + bj[j];
        }
      }
    }
  }
}

// ---------------------------------------------------------------------------
// bf16 MFMA flash attention, S^T formulation. NEW: each block processes TWO
// adjacent 64-query tiles (2*pj, 2*pj+1) against ONE shared K/V stream:
// K/V LDS fragments (MFMA A-operand) are query-independent, so the second
// tile costs zero extra K/V LDS reads -> LDS traffic/unit -42%, staging -48%.
// Diagonal iterations peeled (mask code only there); exp via raw v_exp_f32
// (Q pre-scaled by log2e); s_setprio around MFMA clusters.
// Grid 512 = 16 pair-slots x 32 bh; pj = i<8 ? 15-i : i-8 (bijective,
// heavy blocks dispatch first, co-resident pairs sum to constant work).
// ---------------------------------------------------------------------------
__global__ __launch_bounds__(256, 2) void attn_kernel(
    const short* __restrict__ Qt, const short* __restrict__ Kt,
    const short* __restrict__ Vt, short* __restrict__ attb) {
  const int tid = threadIdx.x;
  const int wave = tid >> 6, lane = tid & 63;
  const int quad = lane >> 4, l16 = lane & 15;

  const int blk = blockIdx.x;
  const int bh = blk & 31;
  const int i = blk >> 5;                       // 0..15
  const int pj = (i < 8) ? (15 - i) : (i - 8);  // pair index, heavy first
  const int NT = 2 * pj + 2;                    // key tiles for this pair
  const int h = bh & 15, b = bh >> 4;

  const short* Qg = Qt + (size_t)bh * 131072;
  const short* Kg = Kt + (size_t)bh * 131072;
  const short* Vg = Vt + (size_t)bh * 131072;

  __shared__ short Ks[2][4096];
  __shared__ short Vs[2][4096];
  __shared__ short Ps[2][4096];

  const int rowl = 16 * wave + l16;

  bf16x8 bq[2][2];
#pragma unroll
  for (int g = 0; g < 2; ++g)
#pragma unroll
    for (int f = 0; f < 2; ++f)
      bq[g][f] = *(const bf16x8*)(Qg +
                 (size_t)((2 * pj + g) * 8 + 4 * f + quad) * 512 + rowl * 8);

  async16(Kg + tid * 8, &Ks[0][tid * 8]);
  async16(Kg + 2048 + tid * 8, &Ks[0][2048 + tid * 8]);
  async16(Vg + tid * 8, &Vs[0][tid * 8]);
  async16(Vg + 2048 + tid * 8, &Vs[0][2048 + tid * 8]);

  f32x4 oacc[4][2] = {};
  float lsum[2] = {0.f, 0.f};

  auto stage_next = [&](int kt) {
    const int dst = (kt + 1) & 1;
    const short* kp = Kg + (size_t)(kt + 1) * 4096;
    const short* vp = Vg + (size_t)(kt + 1) * 4096;
    async16(kp + tid * 8, &Ks[dst][tid * 8]);
    async16(kp + 2048 + tid * 8, &Ks[dst][2048 + tid * 8]);
    async16(vp + tid * 8, &Vs[dst][tid * 8]);
    async16(vp + 2048 + tid * 8, &Vs[dst][2048 + tid * 8]);
  };

  // QK^T for both tiles: one ak read feeds two MFMAs.
  auto qkt2 = [&](int buf, f32x4 (&sacc)[4][2]) {
    __builtin_amdgcn_s_setprio(1);
#pragma unroll
    for (int c = 0; c < 4; ++c) {
#pragma unroll
      for (int f = 0; f < 2; ++f) {
        bf16x8 ak =
            *(const bf16x8*)&Ks[buf][((4 * f + quad) * 64 + 16 * c + l16) * 8];
        sacc[c][0] = __builtin_amdgcn_mfma_f32_16x16x32_bf16(
            ak, bq[0][f], sacc[c][0], 0, 0, 0);
        sacc[c][1] = __builtin_amdgcn_mfma_f32_16x16x32_bf16(
            ak, bq[1][f], sacc[c][1], 0, 0, 0);
      }
    }
    __builtin_amdgcn_s_setprio(0);
  };

  auto smax = [&](f32x4 (&sacc)[4][2], int g, bool mask) {
#pragma unroll
    for (int c = 0; c < 4; ++c) {
      short4 pk;
#pragma unroll
      for (int reg = 0; reg < 4; ++reg) {
        int keyl = 16 * c + 4 * quad + reg;
        float p = (mask && keyl > rowl)
                      ? 0.f
                      : __builtin_amdgcn_exp2f(sacc[c][g][reg]);
        lsum[g] += p;
        ((short*)&pk)[reg] = f2bf(p);
      }
      *(short4*)&Ps[g][(2 * c + (quad >> 1)) * 512 + rowl * 8 + (quad & 1) * 4] =
          pk;
    }
  };

  // PV for both tiles: one bv read feeds two MFMAs.
  auto pv2 = [&](int buf) {
    __asm__ volatile("s_waitcnt lgkmcnt(0)" ::: "memory");
    bf16x8 ap[2][2];
#pragma unroll
    for (int f = 0; f < 2; ++f) {
      ap[0][f] = *(const bf16x8*)&Ps[0][(4 * f + quad) * 512 + rowl * 8];
      ap[1][f] = *(const bf16x8*)&Ps[1][(4 * f + quad) * 512 + rowl * 8];
    }
    __builtin_amdgcn_s_setprio(1);
#pragma unroll
    for (int n = 0; n < 4; ++n) {
#pragma unroll
      for (int f = 0; f < 2; ++f) {
        bf16x8 bv =
            *(const bf16x8*)&Vs[buf][((4 * f + quad) * 64 + 16 * n + l16) * 8];
        oacc[n][0] = __builtin_amdgcn_mfma_f32_16x16x32_bf16(
            ap[0][f], bv, oacc[n][0], 0, 0, 0);
        oacc[n][1] = __builtin_amdgcn_mfma_f32_16x16x32_bf16(
            ap[1][f], bv, oacc[n][1], 0, 0, 0);
      }
    }
    __builtin_amdgcn_s_setprio(0);
  };

  // main loop: kt in [0, NT-2) -- both tiles active, no masks
  for (int kt = 0; kt < NT - 2; ++kt) {
    const int buf = kt & 1;
    __syncthreads();
    stage_next(kt);
    f32x4 sacc[4][2] = {};
    qkt2(buf, sacc);
    smax(sacc, 0, false);
    smax(sacc, 1, false);
    pv2(buf);
  }
  // kt = NT-2: tile0 diagonal (masked), tile1 full
  {
    const int kt = NT - 2, buf = kt & 1;
    __syncthreads();
    stage_next(kt);
    f32x4 sacc[4][2] = {};
    qkt2(buf, sacc);
    smax(sacc, 0, true);
    smax(sacc, 1, false);
    pv2(buf);
  }
  // kt = NT-1: tile1 only, diagonal
  {
    const int buf = (NT - 1) & 1;
    __syncthreads();
    f32x4 sacc1[4] = {};
    __builtin_amdgcn_s_setprio(1);
#pragma unroll
    for (int c = 0; c < 4; ++c)
#pragma unroll
      for (int f = 0; f < 2; ++f) {
        bf16x8 ak =
            *(const bf16x8*)&Ks[buf][((4 * f + quad) * 64 + 16 * c + l16) * 8];
        sacc1[c] = __builtin_amdgcn_mfma_f32_16x16x32_bf16(
            ak, bq[1][f], sacc1[c], 0, 0, 0);
      }
    __builtin_amdgcn_s_setprio(0);
#pragma unroll
    for (int c = 0; c < 4; ++c) {
      short4 pk;
#pragma unroll
      for (int reg = 0; reg < 4; ++reg) {
        int keyl = 16 * c + 4 * quad + reg;
        float p = (keyl > rowl) ? 0.f : __builtin_amdgcn_exp2f(sacc1[c][reg]);
        lsum[1] += p;
        ((short*)&pk)[reg] = f2bf(p);
      }
      *(short4*)&Ps[1][(2 * c + (quad >> 1)) * 512 + rowl * 8 + (quad & 1) * 4] =
          pk;
    }
    __asm__ volatile("s_waitcnt lgkmcnt(0)" ::: "memory");
    bf16x8 ap1[2];
#pragma unroll
    for (int f = 0; f < 2; ++f)
      ap1[f] = *(const bf16x8*)&Ps[1][(4 * f + quad) * 512 + rowl * 8];
    __builtin_amdgcn_s_setprio(1);
#pragma unroll
    for (int n = 0; n < 4; ++n)
#pragma unroll
      for (int f = 0; f < 2; ++f) {
        bf16x8 bv =
            *(const bf16x8*)&Vs[buf][((4 * f + quad) * 64 + 16 * n + l16) * 8];
        oacc[n][1] = __builtin_amdgcn_mfma_f32_16x16x32_bf16(
            ap1[f], bv, oacc[n][1], 0, 0, 0);
      }
    __builtin_amdgcn_s_setprio(0);
  }

  // epilogue per tile
#pragma unroll
  for (int g = 0; g < 2; ++g) {
    float ls = lsum[g];
    ls += __shfl_xor(ls, 16);
    ls += __shfl_xor(ls, 32);
    float linv[4];
#pragma unroll
    for (int reg = 0; reg < 4; ++reg)
      linv[reg] = 1.0f / __shfl(ls, 4 * quad + reg, 64);
#pragma unroll
    for (int reg = 0; reg < 4; ++reg) {
      const int row = (2 * pj + g) * 64 + 16 * wave + 4 * quad + reg;
      const int m = b * T_ + row;
      const int xv = (m >> 1) & 3;
#pragma unroll
      for (int n = 0; n < 4; ++n) {
        int c = h * 64 + 16 * n + l16;
        int cs = (c & ~31) | ((((c >> 3) & 3) ^ xv) << 3) | (c & 7);
        attb[(size_t)m * C_ + cs] = f2bf(oacc[n][g][reg] * linv[reg]);
      }
    }
  }
}

extern "C" void kernel_launch(void* const* d_in, const int* in_sizes, int n_in,
                              void* d_out, int out_size, void* d_ws, size_t ws_size,
                              hipStream_t stream) {
  const float* x      = (const float*)d_in[0];
  const float* w_qkv  = (const float*)d_in[1];
  const float* b_qkv  = (const float*)d_in[2];
  const float* w_proj = (const float*)d_in[3];
  const float* b_proj = (const float*)d_in[4];
  float* out = (float*)d_out;

  const size_t per = (size_t)B_ * H_ * T_ * D_;  // 4.19M
  short* Qp   = (short*)d_ws;
  short* Kp   = Qp + per;
  short* Vp   = Kp + per;
  short* attb = Vp + per;                   // [4096,1024] bf16 swizzled
  short* xb   = attb + per;                 // [4096,1024] bf16 swizzled
  short* wqt  = xb + per;                   // [3072,1024] bf16 swizzled
  short* wpt  = wqt + (size_t)3 * C_ * C_;  // [1024,1024] bf16 swizzled

  prep<<<1536, 256, 0, stream>>>(x, w_qkv, w_proj, xb, wqt, wpt);

  gemm_mfma<3 * C_, 128, true><<<dim3(24, 32), 256, 0, stream>>>(
      xb, wqt, b_qkv, Qp, Kp, Vp, nullptr);

  attn_kernel<<<dim3(512), 256, 0, stream>>>(Qp, Kp, Vp, attb);

  gemm_mfma<C_, 64, false><<<dim3(16, 32), 256, 0, stream>>>(
      attb, wpt, b_proj, nullptr, nullptr, nullptr, out);
}

// Round 2
// 179.072 us; speedup vs baseline: 1.0020x; 1.0020x over previous
//
#include <hip/hip_runtime.h>
#include <hip/hip_bf16.h>
#include <math.h>
#include <stdint.h>

#define B_ 2
#define T_ 2048
#define C_ 1024
#define H_ 16
#define D_ 64

typedef __attribute__((ext_vector_type(8))) short bf16x8;
typedef __attribute__((ext_vector_type(4))) float f32x4;

__device__ inline short f2bf(float f) {
  __hip_bfloat16 h = __float2bfloat16(f);
  return *(short*)&h;
}

// async global->LDS, 16B/lane. LDS image = wave-uniform base + lane*16.
__device__ inline void async16(const void* g, void* l) {
  __builtin_amdgcn_global_load_lds(
      (const __attribute__((address_space(1))) uint32_t*)g,
      (__attribute__((address_space(3))) uint32_t*)l, 16, 0, 0);
}

// ---------------------------------------------------------------------------
// Swizzle convention for GEMM operand images (A [M,1024] and B^T [N,1024]):
// chunk p of each 32-k group holds source chunk (p ^ ((row>>1)&3)).
// Fragment reads use chunk (quad ^ ((l16>>1)&3)) -> 2-way banks (free).
// ---------------------------------------------------------------------------

// One prep kernel: blocks [0,512) convert x -> bf16 swizzled (coalesced:
// each pass one full 4KB row per block); [512,1280) transpose w_qkv;
// [1280,1536) transpose w_proj.
__global__ __launch_bounds__(256) void prep(
    const float* __restrict__ X, const float* __restrict__ Wq,
    const float* __restrict__ Wp, short* __restrict__ Xb,
    short* __restrict__ Wqt, short* __restrict__ Wpt) {
  const int tid = threadIdx.x;
  const int blk = blockIdx.x;
  __shared__ short Ts[64][68];

  if (blk < 512) {  // convert_x: 8 rows per block, 1 row (1024 f32) per pass
    const int g = tid >> 3;        // 32-float group in row
    const int sub = tid & 7;       // 4-float slot in group
    const int sc = sub >> 1;       // source chunk 0..3
    const int e4 = (sub & 1) * 4;
#pragma unroll
    for (int pass = 0; pass < 8; ++pass) {
      const int m = blk * 8 + pass;
      float4 v = *(const float4*)(X + (size_t)m * C_ + tid * 4);
      const int xv = (m >> 1) & 3;
      short o[4] = {f2bf(v.x), f2bf(v.y), f2bf(v.z), f2bf(v.w)};
      *(uint2*)(Xb + (size_t)m * C_ + g * 32 + ((sc ^ xv) << 3) + e4) =
          *(uint2*)o;
    }
    return;
  }

  const float* W;
  short* Wt;
  int N, n0, k0;
  if (blk < 1280) {
    int i = blk - 512;
    W = Wq; Wt = Wqt; N = 3 * C_;
    n0 = (i % 48) * 64; k0 = (i / 48) * 64;
  } else {
    int i = blk - 1280;
    W = Wp; Wt = Wpt; N = C_;
    n0 = (i & 15) * 64; k0 = (i >> 4) * 64;
  }
  {
    int r = tid >> 2, c0 = (tid & 3) * 16;
    const float* src = W + (size_t)(k0 + r) * N + n0 + c0;
#pragma unroll
    for (int u = 0; u < 16; u += 4) {
      float4 v = *(const float4*)(src + u);
      Ts[r][c0 + u + 0] = f2bf(v.x);
      Ts[r][c0 + u + 1] = f2bf(v.y);
      Ts[r][c0 + u + 2] = f2bf(v.z);
      Ts[r][c0 + u + 3] = f2bf(v.w);
    }
  }
  __syncthreads();
  // write: 8 lanes cover one output row's 64 k (128 B contiguous, coalesced)
#pragma unroll
  for (int p = 0; p < 2; ++p) {
    int n = (tid >> 3) + p * 32;
    int kc = tid & 7;
    int xv = ((n0 + n) >> 1) & 3;
    int ka = kc * 8;
    int dk = (ka & ~31) | ((((ka >> 3) & 3) ^ xv) << 3);
    short tmp[8];
#pragma unroll
    for (int u = 0; u < 8; ++u) tmp[u] = Ts[ka + u][n];
    *(uint4*)(Wt + (size_t)(n0 + n) * 1024 + k0 + dk) = *(uint4*)tmp;
  }
}

// ---------------------------------------------------------------------------
// bf16 MFMA GEMM, 128xBN tile. NEW: triple-buffered BK=32 pipeline with
// counted vmcnt (T3-minimum + T4): per step, issue next stage's
// global_load_lds BEFORE waiting, then s_waitcnt vmcnt(L) (never 0 in the
// main loop), ONE raw s_barrier, then ds_read+MFMA. Buffer (t+1)%3's writes
// are separated from its last reads (iter t-2) by the barrier at t-1.
// LDS: BN=128 -> 48KB, BN=64 -> 36KB (3 blocks/CU either way).
// QKV=true (BN=128): scatter epilogue -> attention-tiled Q/K/V:
//   Q,K: [bh][t>>6][d>>3][t&63][d&7]   (per-bh stride 131072 shorts)
//   V:   [bh][t>>6][(t&63)>>3][d][t&7].
// Q is pre-scaled by (1/sqrt(D))*log2(e) so attention uses raw exp2.
// ---------------------------------------------------------------------------
template <int N, int BN, bool QKV>
__global__ __launch_bounds__(256, 3) void gemm_mfma(
    const short* __restrict__ A, const short* __restrict__ Bt,
    const float* __restrict__ bias, short* __restrict__ Qp,
    short* __restrict__ Kp, short* __restrict__ Vp, float* __restrict__ Cout) {
  constexpr int NJ = BN / 32;      // n-tiles per wave
  constexpr int BI = BN * 32;      // B image size (shorts) per BK=32 stage
  const int tid = threadIdx.x;
  const int wave = tid >> 6, lane = tid & 63;
  const int quad = lane >> 4, l16 = lane & 15;
  const int wm = wave >> 1, wn = wave & 1;
  const int m0 = blockIdx.y * 128, n0 = blockIdx.x * BN;

  __shared__ short As[3][4096];    // 128 rows x 32k, swizzled
  __shared__ short Bs[3][BI];      // BN rows x 32k, swizzled

  const int srow = tid >> 2, skc = tid & 3;
  const size_t arow0 = (size_t)(m0 + srow) * 1024 + skc * 8;
  const size_t brow0 = (size_t)(n0 + srow) * 1024 + skc * 8;

  f32x4 acc[4][NJ] = {};

  const int xi = quad ^ ((l16 >> 1) & 3);  // de-swizzle chunk select
  int aoff[4], boff[NJ];
#pragma unroll
  for (int i = 0; i < 4; ++i) aoff[i] = (wm * 64 + i * 16 + l16) * 32 + xi * 8;
#pragma unroll
  for (int j = 0; j < NJ; ++j)
    boff[j] = (wn * (BN / 2) + j * 16 + l16) * 32 + xi * 8;

  auto stage = [&](int t) {
    const int s = t % 3;
    const size_t kf = (size_t)t * 32;
    async16(A + arow0 + kf, &As[s][tid * 8]);
    async16(A + arow0 + (size_t)64 * 1024 + kf, &As[s][2048 + tid * 8]);
    async16(Bt + brow0 + kf, &Bs[s][tid * 8]);
    if (BN == 128)
      async16(Bt + brow0 + (size_t)64 * 1024 + kf, &Bs[s][2048 + tid * 8]);
  };

  stage(0);
  for (int t = 0; t < 32; ++t) {
    const int s = t % 3;
    if (t + 1 < 32) {
      stage(t + 1);
      // wait for tile t's loads (the L just-issued stay in flight)
      if constexpr (BN == 128)
        __asm__ volatile("s_waitcnt vmcnt(4)" ::: "memory");
      else
        __asm__ volatile("s_waitcnt vmcnt(3)" ::: "memory");
    } else {
      __asm__ volatile("s_waitcnt vmcnt(0)" ::: "memory");
    }
    __builtin_amdgcn_s_barrier();

    bf16x8 af[4], bfr[NJ];
#pragma unroll
    for (int i = 0; i < 4; ++i) af[i] = *(const bf16x8*)&As[s][aoff[i]];
#pragma unroll
    for (int j = 0; j < NJ; ++j) bfr[j] = *(const bf16x8*)&Bs[s][boff[j]];
#pragma unroll
    for (int i = 0; i < 4; ++i)
#pragma unroll
      for (int j = 0; j < NJ; ++j)
        acc[i][j] = __builtin_amdgcn_mfma_f32_16x16x32_bf16(
            af[i], bfr[j], acc[i][j], 0, 0, 0);
  }

  float bj[NJ];
#pragma unroll
  for (int j = 0; j < NJ; ++j) bj[j] = bias[n0 + wn * (BN / 2) + j * 16 + l16];

  if (QKV) {
#pragma unroll
    for (int i = 0; i < 4; ++i) {
#pragma unroll
      for (int reg = 0; reg < 4; ++reg) {
        int m = m0 + wm * 64 + i * 16 + quad * 4 + reg;
        int b = m >> 11, t = m & (T_ - 1);
#pragma unroll
        for (int j = 0; j < NJ; ++j) {
          int n = n0 + wn * (BN / 2) + j * 16 + l16;
          float v = acc[i][j][reg] + bj[j];
          int sel = n >> 10, cc = n & (C_ - 1);
          int hh = cc >> 6, d = cc & 63;
          size_t base = (size_t)(b * H_ + hh) * 131072 + (size_t)(t >> 6) * 4096;
          if (sel == 0) {
            // 0.125 * log2(e) = 0.18033688011
            Qp[base + (d >> 3) * 512 + (t & 63) * 8 + (d & 7)] =
                f2bf(v * 0.18033688011112042f);
          } else if (sel == 1) {
            Kp[base + (d >> 3) * 512 + (t & 63) * 8 + (d & 7)] = f2bf(v);
          } else {
            Vp[base + ((t & 63) >> 3) * 512 + d * 8 + (t & 7)] = f2bf(v);
          }
        }
      }
    }
  } else {
#pragma unroll
    for (int i = 0; i < 4; ++i) {
#pragma unroll
      for (int reg = 0; reg < 4; ++reg) {
        int m = m0 + wm * 64 + i * 16 + quad * 4 + reg;
#pragma unroll
        for (int j = 0; j < NJ; ++j) {
          int n = n0 + wn * (BN / 2) + j * 16 + l16;
          Cout[(size_t)m * N + n] = acc[i][j][reg] + bj[j];
        }
      }
    }
  }
}

// ---------------------------------------------------------------------------
// bf16 MFMA flash attention, S^T formulation. Each block processes TWO
// adjacent 64-query tiles (2*pj, 2*pj+1) against ONE shared K/V stream:
// K/V LDS fragments (MFMA A-operand) are query-independent, so the second
// tile costs zero extra K/V LDS reads. Diagonal iterations peeled; exp via
// raw v_exp_f32 (Q pre-scaled by log2e); s_setprio around MFMA clusters.
// Grid 512 = 16 pair-slots x 32 bh; pj = i<8 ? 15-i : i-8 (bijective,
// heavy blocks dispatch first, co-resident pairs sum to constant work).
// ---------------------------------------------------------------------------
__global__ __launch_bounds__(256, 2) void attn_kernel(
    const short* __restrict__ Qt, const short* __restrict__ Kt,
    const short* __restrict__ Vt, short* __restrict__ attb) {
  const int tid = threadIdx.x;
  const int wave = tid >> 6, lane = tid & 63;
  const int quad = lane >> 4, l16 = lane & 15;

  const int blk = blockIdx.x;
  const int bh = blk & 31;
  const int i = blk >> 5;                       // 0..15
  const int pj = (i < 8) ? (15 - i) : (i - 8);  // pair index, heavy first
  const int NT = 2 * pj + 2;                    // key tiles for this pair
  const int h = bh & 15, b = bh >> 4;

  const short* Qg = Qt + (size_t)bh * 131072;
  const short* Kg = Kt + (size_t)bh * 131072;
  const short* Vg = Vt + (size_t)bh * 131072;

  __shared__ short Ks[2][4096];
  __shared__ short Vs[2][4096];
  __shared__ short Ps[2][4096];

  const int rowl = 16 * wave + l16;

  bf16x8 bq[2][2];
#pragma unroll
  for (int g = 0; g < 2; ++g)
#pragma unroll
    for (int f = 0; f < 2; ++f)
      bq[g][f] = *(const bf16x8*)(Qg +
                 (size_t)((2 * pj + g) * 8 + 4 * f + quad) * 512 + rowl * 8);

  async16(Kg + tid * 8, &Ks[0][tid * 8]);
  async16(Kg + 2048 + tid * 8, &Ks[0][2048 + tid * 8]);
  async16(Vg + tid * 8, &Vs[0][tid * 8]);
  async16(Vg + 2048 + tid * 8, &Vs[0][2048 + tid * 8]);

  f32x4 oacc[4][2] = {};
  float lsum[2] = {0.f, 0.f};

  auto stage_next = [&](int kt) {
    const int dst = (kt + 1) & 1;
    const short* kp = Kg + (size_t)(kt + 1) * 4096;
    const short* vp = Vg + (size_t)(kt + 1) * 4096;
    async16(kp + tid * 8, &Ks[dst][tid * 8]);
    async16(kp + 2048 + tid * 8, &Ks[dst][2048 + tid * 8]);
    async16(vp + tid * 8, &Vs[dst][tid * 8]);
    async16(vp + 2048 + tid * 8, &Vs[dst][2048 + tid * 8]);
  };

  // QK^T for both tiles: one ak read feeds two MFMAs.
  auto qkt2 = [&](int buf, f32x4 (&sacc)[4][2]) {
    __builtin_amdgcn_s_setprio(1);
#pragma unroll
    for (int c = 0; c < 4; ++c) {
#pragma unroll
      for (int f = 0; f < 2; ++f) {
        bf16x8 ak =
            *(const bf16x8*)&Ks[buf][((4 * f + quad) * 64 + 16 * c + l16) * 8];
        sacc[c][0] = __builtin_amdgcn_mfma_f32_16x16x32_bf16(
            ak, bq[0][f], sacc[c][0], 0, 0, 0);
        sacc[c][1] = __builtin_amdgcn_mfma_f32_16x16x32_bf16(
            ak, bq[1][f], sacc[c][1], 0, 0, 0);
      }
    }
    __builtin_amdgcn_s_setprio(0);
  };

  auto smax = [&](f32x4 (&sacc)[4][2], int g, bool mask) {
#pragma unroll
    for (int c = 0; c < 4; ++c) {
      short4 pk;
#pragma unroll
      for (int reg = 0; reg < 4; ++reg) {
        int keyl = 16 * c + 4 * quad + reg;
        float p = (mask && keyl > rowl)
                      ? 0.f
                      : __builtin_amdgcn_exp2f(sacc[c][g][reg]);
        lsum[g] += p;
        ((short*)&pk)[reg] = f2bf(p);
      }
      *(short4*)&Ps[g][(2 * c + (quad >> 1)) * 512 + rowl * 8 + (quad & 1) * 4] =
          pk;
    }
  };

  // PV for both tiles: one bv read feeds two MFMAs.
  auto pv2 = [&](int buf) {
    __asm__ volatile("s_waitcnt lgkmcnt(0)" ::: "memory");
    bf16x8 ap[2][2];
#pragma unroll
    for (int f = 0; f < 2; ++f) {
      ap[0][f] = *(const bf16x8*)&Ps[0][(4 * f + quad) * 512 + rowl * 8];
      ap[1][f] = *(const bf16x8*)&Ps[1][(4 * f + quad) * 512 + rowl * 8];
    }
    __builtin_amdgcn_s_setprio(1);
#pragma unroll
    for (int n = 0; n < 4; ++n) {
#pragma unroll
      for (int f = 0; f < 2; ++f) {
        bf16x8 bv =
            *(const bf16x8*)&Vs[buf][((4 * f + quad) * 64 + 16 * n + l16) * 8];
        oacc[n][0] = __builtin_amdgcn_mfma_f32_16x16x32_bf16(
            ap[0][f], bv, oacc[n][0], 0, 0, 0);
        oacc[n][1] = __builtin_amdgcn_mfma_f32_16x16x32_bf16(
            ap[1][f], bv, oacc[n][1], 0, 0, 0);
      }
    }
    __builtin_amdgcn_s_setprio(0);
  };

  // main loop: kt in [0, NT-2) -- both tiles active, no masks
  for (int kt = 0; kt < NT - 2; ++kt) {
    const int buf = kt & 1;
    __syncthreads();
    stage_next(kt);
    f32x4 sacc[4][2] = {};
    qkt2(buf, sacc);
    smax(sacc, 0, false);
    smax(sacc, 1, false);
    pv2(buf);
  }
  // kt = NT-2: tile0 diagonal (masked), tile1 full
  {
    const int kt = NT - 2, buf = kt & 1;
    __syncthreads();
    stage_next(kt);
    f32x4 sacc[4][2] = {};
    qkt2(buf, sacc);
    smax(sacc, 0, true);
    smax(sacc, 1, false);
    pv2(buf);
  }
  // kt = NT-1: tile1 only, diagonal
  {
    const int buf = (NT - 1) & 1;
    __syncthreads();
    f32x4 sacc1[4] = {};
    __builtin_amdgcn_s_setprio(1);
#pragma unroll
    for (int c = 0; c < 4; ++c)
#pragma unroll
      for (int f = 0; f < 2; ++f) {
        bf16x8 ak =
            *(const bf16x8*)&Ks[buf][((4 * f + quad) * 64 + 16 * c + l16) * 8];
        sacc1[c] = __builtin_amdgcn_mfma_f32_16x16x32_bf16(
            ak, bq[1][f], sacc1[c], 0, 0, 0);
      }
    __builtin_amdgcn_s_setprio(0);
#pragma unroll
    for (int c = 0; c < 4; ++c) {
      short4 pk;
#pragma unroll
      for (int reg = 0; reg < 4; ++reg) {
        int keyl = 16 * c + 4 * quad + reg;
        float p = (keyl > rowl) ? 0.f : __builtin_amdgcn_exp2f(sacc1[c][reg]);
        lsum[1] += p;
        ((short*)&pk)[reg] = f2bf(p);
      }
      *(short4*)&Ps[1][(2 * c + (quad >> 1)) * 512 + rowl * 8 + (quad & 1) * 4] =
          pk;
    }
    __asm__ volatile("s_waitcnt lgkmcnt(0)" ::: "memory");
    bf16x8 ap1[2];
#pragma unroll
    for (int f = 0; f < 2; ++f)
      ap1[f] = *(const bf16x8*)&Ps[1][(4 * f + quad) * 512 + rowl * 8];
    __builtin_amdgcn_s_setprio(1);
#pragma unroll
    for (int n = 0; n < 4; ++n)
#pragma unroll
      for (int f = 0; f < 2; ++f) {
        bf16x8 bv =
            *(const bf16x8*)&Vs[buf][((4 * f + quad) * 64 + 16 * n + l16) * 8];
        oacc[n][1] = __builtin_amdgcn_mfma_f32_16x16x32_bf16(
            ap1[f], bv, oacc[n][1], 0, 0, 0);
      }
    __builtin_amdgcn_s_setprio(0);
  }

  // epilogue per tile
#pragma unroll
  for (int g = 0; g < 2; ++g) {
    float ls = lsum[g];
    ls += __shfl_xor(ls, 16);
    ls += __shfl_xor(ls, 32);
    float linv[4];
#pragma unroll
    for (int reg = 0; reg < 4; ++reg)
      linv[reg] = 1.0f / __shfl(ls, 4 * quad + reg, 64);
#pragma unroll
    for (int reg = 0; reg < 4; ++reg) {
      const int row = (2 * pj + g) * 64 + 16 * wave + 4 * quad + reg;
      const int m = b * T_ + row;
      const int xv = (m >> 1) & 3;
#pragma unroll
      for (int n = 0; n < 4; ++n) {
        int c = h * 64 + 16 * n + l16;
        int cs = (c & ~31) | ((((c >> 3) & 3) ^ xv) << 3) | (c & 7);
        attb[(size_t)m * C_ + cs] = f2bf(oacc[n][g][reg] * linv[reg]);
      }
    }
  }
}

extern "C" void kernel_launch(void* const* d_in, const int* in_sizes, int n_in,
                              void* d_out, int out_size, void* d_ws, size_t ws_size,
                              hipStream_t stream) {
  const float* x      = (const float*)d_in[0];
  const float* w_qkv  = (const float*)d_in[1];
  const float* b_qkv  = (const float*)d_in[2];
  const float* w_proj = (const float*)d_in[3];
  const float* b_proj = (const float*)d_in[4];
  float* out = (float*)d_out;

  const size_t per = (size_t)B_ * H_ * T_ * D_;  // 4.19M
  short* Qp   = (short*)d_ws;
  short* Kp   = Qp + per;
  short* Vp   = Kp + per;
  short* attb = Vp + per;                   // [4096,1024] bf16 swizzled
  short* xb   = attb + per;                 // [4096,1024] bf16 swizzled
  short* wqt  = xb + per;                   // [3072,1024] bf16 swizzled
  short* wpt  = wqt + (size_t)3 * C_ * C_;  // [1024,1024] bf16 swizzled

  prep<<<1536, 256, 0, stream>>>(x, w_qkv, w_proj, xb, wqt, wpt);

  gemm_mfma<3 * C_, 128, true><<<dim3(24, 32), 256, 0, stream>>>(
      xb, wqt, b_qkv, Qp, Kp, Vp, nullptr);

  attn_kernel<<<dim3(512), 256, 0, stream>>>(Qp, Kp, Vp, attb);

  gemm_mfma<C_, 64, false><<<dim3(16, 32), 256, 0, stream>>>(
      attb, wpt, b_proj, nullptr, nullptr, nullptr, out);
}

// Round 3
// 178.774 us; speedup vs baseline: 1.0037x; 1.0017x over previous
//
#include <hip/hip_runtime.h>
#include <hip/hip_bf16.h>
#include <math.h>
#include <stdint.h>

#define B_ 2
#define T_ 2048
#define C_ 1024
#define H_ 16
#define D_ 64

typedef __attribute__((ext_vector_type(8))) short bf16x8;
typedef __attribute__((ext_vector_type(4))) float f32x4;

__device__ inline short f2bf(float f) {
  __hip_bfloat16 h = __float2bfloat16(f);
  return *(short*)&h;
}

// async global->LDS, 16B/lane. LDS image = wave-uniform base + lane*16.
__device__ inline void async16(const void* g, void* l) {
  __builtin_amdgcn_global_load_lds(
      (const __attribute__((address_space(1))) uint32_t*)g,
      (__attribute__((address_space(3))) uint32_t*)l, 16, 0, 0);
}

// ---------------------------------------------------------------------------
// Swizzle convention for GEMM operand images (A [M,1024] and B^T [N,1024]):
// chunk p of each 32-k group holds source chunk (p ^ ((row>>1)&3)).
// Fragment reads use chunk (quad ^ ((l16>>1)&3)) -> 2-way banks (free).
// ---------------------------------------------------------------------------

// One prep kernel: blocks [0,512) convert x -> bf16 swizzled (coalesced:
// each pass one full 4KB row per block); [512,1280) transpose w_qkv;
// [1280,1536) transpose w_proj.
__global__ __launch_bounds__(256) void prep(
    const float* __restrict__ X, const float* __restrict__ Wq,
    const float* __restrict__ Wp, short* __restrict__ Xb,
    short* __restrict__ Wqt, short* __restrict__ Wpt) {
  const int tid = threadIdx.x;
  const int blk = blockIdx.x;
  __shared__ short Ts[64][68];

  if (blk < 512) {  // convert_x: 8 rows per block, 1 row (1024 f32) per pass
    const int g = tid >> 3;        // 32-float group in row
    const int sub = tid & 7;       // 4-float slot in group
    const int sc = sub >> 1;       // source chunk 0..3
    const int e4 = (sub & 1) * 4;
#pragma unroll
    for (int pass = 0; pass < 8; ++pass) {
      const int m = blk * 8 + pass;
      float4 v = *(const float4*)(X + (size_t)m * C_ + tid * 4);
      const int xv = (m >> 1) & 3;
      short o[4] = {f2bf(v.x), f2bf(v.y), f2bf(v.z), f2bf(v.w)};
      *(uint2*)(Xb + (size_t)m * C_ + g * 32 + ((sc ^ xv) << 3) + e4) =
          *(uint2*)o;
    }
    return;
  }

  const float* W;
  short* Wt;
  int N, n0, k0;
  if (blk < 1280) {
    int i = blk - 512;
    W = Wq; Wt = Wqt; N = 3 * C_;
    n0 = (i % 48) * 64; k0 = (i / 48) * 64;
  } else {
    int i = blk - 1280;
    W = Wp; Wt = Wpt; N = C_;
    n0 = (i & 15) * 64; k0 = (i >> 4) * 64;
  }
  {
    int r = tid >> 2, c0 = (tid & 3) * 16;
    const float* src = W + (size_t)(k0 + r) * N + n0 + c0;
#pragma unroll
    for (int u = 0; u < 16; u += 4) {
      float4 v = *(const float4*)(src + u);
      Ts[r][c0 + u + 0] = f2bf(v.x);
      Ts[r][c0 + u + 1] = f2bf(v.y);
      Ts[r][c0 + u + 2] = f2bf(v.z);
      Ts[r][c0 + u + 3] = f2bf(v.w);
    }
  }
  __syncthreads();
  // write: 8 lanes cover one output row's 64 k (128 B contiguous, coalesced)
#pragma unroll
  for (int p = 0; p < 2; ++p) {
    int n = (tid >> 3) + p * 32;
    int kc = tid & 7;
    int xv = ((n0 + n) >> 1) & 3;
    int ka = kc * 8;
    int dk = (ka & ~31) | ((((ka >> 3) & 3) ^ xv) << 3);
    short tmp[8];
#pragma unroll
    for (int u = 0; u < 8; ++u) tmp[u] = Ts[ka + u][n];
    *(uint4*)(Wt + (size_t)(n0 + n) * 1024 + k0 + dk) = *(uint4*)tmp;
  }
}

// ---------------------------------------------------------------------------
// bf16 MFMA GEMM, 128xBN tile, triple-buffered BK=32 pipeline with counted
// vmcnt. NEW (round 3): XCD-rectangle block swizzle. Dispatch round-robins
// flat id across 8 XCDs (id%8 = xcd); each XCD gets a CONTIGUOUS rectangle
// of the output grid so its co-resident blocks' operand panels fit the 4MB
// per-XCD L2:
//   QKV (32x24 grid): 8 rects of 8(by) x 12(bx) -> A 2MB + B 3MB per XCD
//   proj (32x16 grid): 8 rects of 8 x 8        -> A 2MB + B 1MB per XCD
// 1-D launch; in-kernel decode. Pure bijective remap, no sync changes.
// ---------------------------------------------------------------------------
template <int N, int BN, bool QKV>
__global__ __launch_bounds__(256, 3) void gemm_mfma(
    const short* __restrict__ A, const short* __restrict__ Bt,
    const float* __restrict__ bias, short* __restrict__ Qp,
    short* __restrict__ Kp, short* __restrict__ Vp, float* __restrict__ Cout) {
  constexpr int NJ = BN / 32;      // n-tiles per wave
  constexpr int BI = BN * 32;      // B image size (shorts) per BK=32 stage
  constexpr int NBX = (N == 3 * C_) ? 24 : 16;  // grid cols
  constexpr int CCOL = NBX / 2;    // rect cols (12 or 8)
  const int tid = threadIdx.x;
  const int wave = tid >> 6, lane = tid & 63;
  const int quad = lane >> 4, l16 = lane & 15;
  const int wm = wave >> 1, wn = wave & 1;

  const int f = blockIdx.x;
  const int xcd = f & 7, r = f >> 3;
  const int lby = r / CCOL, lbx = r - lby * CCOL;
  const int by = (xcd >> 1) * 8 + lby;
  const int bx = (xcd & 1) * CCOL + lbx;
  const int m0 = by * 128, n0 = bx * BN;

  __shared__ short As[3][4096];    // 128 rows x 32k, swizzled
  __shared__ short Bs[3][BI];      // BN rows x 32k, swizzled

  const int srow = tid >> 2, skc = tid & 3;
  const size_t arow0 = (size_t)(m0 + srow) * 1024 + skc * 8;
  const size_t brow0 = (size_t)(n0 + srow) * 1024 + skc * 8;

  f32x4 acc[4][NJ] = {};

  const int xi = quad ^ ((l16 >> 1) & 3);  // de-swizzle chunk select
  int aoff[4], boff[NJ];
#pragma unroll
  for (int i = 0; i < 4; ++i) aoff[i] = (wm * 64 + i * 16 + l16) * 32 + xi * 8;
#pragma unroll
  for (int j = 0; j < NJ; ++j)
    boff[j] = (wn * (BN / 2) + j * 16 + l16) * 32 + xi * 8;

  auto stage = [&](int t) {
    const int s = t % 3;
    const size_t kf = (size_t)t * 32;
    async16(A + arow0 + kf, &As[s][tid * 8]);
    async16(A + arow0 + (size_t)64 * 1024 + kf, &As[s][2048 + tid * 8]);
    async16(Bt + brow0 + kf, &Bs[s][tid * 8]);
    if (BN == 128)
      async16(Bt + brow0 + (size_t)64 * 1024 + kf, &Bs[s][2048 + tid * 8]);
  };

  stage(0);
  for (int t = 0; t < 32; ++t) {
    const int s = t % 3;
    if (t + 1 < 32) {
      stage(t + 1);
      if constexpr (BN == 128)
        __asm__ volatile("s_waitcnt vmcnt(4)" ::: "memory");
      else
        __asm__ volatile("s_waitcnt vmcnt(3)" ::: "memory");
    } else {
      __asm__ volatile("s_waitcnt vmcnt(0)" ::: "memory");
    }
    __builtin_amdgcn_s_barrier();

    bf16x8 af[4], bfr[NJ];
#pragma unroll
    for (int i = 0; i < 4; ++i) af[i] = *(const bf16x8*)&As[s][aoff[i]];
#pragma unroll
    for (int j = 0; j < NJ; ++j) bfr[j] = *(const bf16x8*)&Bs[s][boff[j]];
#pragma unroll
    for (int i = 0; i < 4; ++i)
#pragma unroll
      for (int j = 0; j < NJ; ++j)
        acc[i][j] = __builtin_amdgcn_mfma_f32_16x16x32_bf16(
            af[i], bfr[j], acc[i][j], 0, 0, 0);
  }

  float bj[NJ];
#pragma unroll
  for (int j = 0; j < NJ; ++j) bj[j] = bias[n0 + wn * (BN / 2) + j * 16 + l16];

  if (QKV) {
#pragma unroll
    for (int i = 0; i < 4; ++i) {
#pragma unroll
      for (int reg = 0; reg < 4; ++reg) {
        int m = m0 + wm * 64 + i * 16 + quad * 4 + reg;
        int b = m >> 11, t = m & (T_ - 1);
#pragma unroll
        for (int j = 0; j < NJ; ++j) {
          int n = n0 + wn * (BN / 2) + j * 16 + l16;
          float v = acc[i][j][reg] + bj[j];
          int sel = n >> 10, cc = n & (C_ - 1);
          int hh = cc >> 6, d = cc & 63;
          size_t base = (size_t)(b * H_ + hh) * 131072 + (size_t)(t >> 6) * 4096;
          if (sel == 0) {
            // 0.125 * log2(e) = 0.18033688011
            Qp[base + (d >> 3) * 512 + (t & 63) * 8 + (d & 7)] =
                f2bf(v * 0.18033688011112042f);
          } else if (sel == 1) {
            Kp[base + (d >> 3) * 512 + (t & 63) * 8 + (d & 7)] = f2bf(v);
          } else {
            Vp[base + ((t & 63) >> 3) * 512 + d * 8 + (t & 7)] = f2bf(v);
          }
        }
      }
    }
  } else {
#pragma unroll
    for (int i = 0; i < 4; ++i) {
#pragma unroll
      for (int reg = 0; reg < 4; ++reg) {
        int m = m0 + wm * 64 + i * 16 + quad * 4 + reg;
#pragma unroll
        for (int j = 0; j < NJ; ++j) {
          int n = n0 + wn * (BN / 2) + j * 16 + l16;
          Cout[(size_t)m * N + n] = acc[i][j][reg] + bj[j];
        }
      }
    }
  }
}

// ---------------------------------------------------------------------------
// bf16 MFMA flash attention, S^T formulation, paired 64-query tiles
// (unchanged from round 2; verified).
// ---------------------------------------------------------------------------
__global__ __launch_bounds__(256, 2) void attn_kernel(
    const short* __restrict__ Qt, const short* __restrict__ Kt,
    const short* __restrict__ Vt, short* __restrict__ attb) {
  const int tid = threadIdx.x;
  const int wave = tid >> 6, lane = tid & 63;
  const int quad = lane >> 4, l16 = lane & 15;

  const int blk = blockIdx.x;
  const int bh = blk & 31;
  const int i = blk >> 5;                       // 0..15
  const int pj = (i < 8) ? (15 - i) : (i - 8);  // pair index, heavy first
  const int NT = 2 * pj + 2;                    // key tiles for this pair
  const int h = bh & 15, b = bh >> 4;

  const short* Qg = Qt + (size_t)bh * 131072;
  const short* Kg = Kt + (size_t)bh * 131072;
  const short* Vg = Vt + (size_t)bh * 131072;

  __shared__ short Ks[2][4096];
  __shared__ short Vs[2][4096];
  __shared__ short Ps[2][4096];

  const int rowl = 16 * wave + l16;

  bf16x8 bq[2][2];
#pragma unroll
  for (int g = 0; g < 2; ++g)
#pragma unroll
    for (int f = 0; f < 2; ++f)
      bq[g][f] = *(const bf16x8*)(Qg +
                 (size_t)((2 * pj + g) * 8 + 4 * f + quad) * 512 + rowl * 8);

  async16(Kg + tid * 8, &Ks[0][tid * 8]);
  async16(Kg + 2048 + tid * 8, &Ks[0][2048 + tid * 8]);
  async16(Vg + tid * 8, &Vs[0][tid * 8]);
  async16(Vg + 2048 + tid * 8, &Vs[0][2048 + tid * 8]);

  f32x4 oacc[4][2] = {};
  float lsum[2] = {0.f, 0.f};

  auto stage_next = [&](int kt) {
    const int dst = (kt + 1) & 1;
    const short* kp = Kg + (size_t)(kt + 1) * 4096;
    const short* vp = Vg + (size_t)(kt + 1) * 4096;
    async16(kp + tid * 8, &Ks[dst][tid * 8]);
    async16(kp + 2048 + tid * 8, &Ks[dst][2048 + tid * 8]);
    async16(vp + tid * 8, &Vs[dst][tid * 8]);
    async16(vp + 2048 + tid * 8, &Vs[dst][2048 + tid * 8]);
  };

  auto qkt2 = [&](int buf, f32x4 (&sacc)[4][2]) {
    __builtin_amdgcn_s_setprio(1);
#pragma unroll
    for (int c = 0; c < 4; ++c) {
#pragma unroll
      for (int f = 0; f < 2; ++f) {
        bf16x8 ak =
            *(const bf16x8*)&Ks[buf][((4 * f + quad) * 64 + 16 * c + l16) * 8];
        sacc[c][0] = __builtin_amdgcn_mfma_f32_16x16x32_bf16(
            ak, bq[0][f], sacc[c][0], 0, 0, 0);
        sacc[c][1] = __builtin_amdgcn_mfma_f32_16x16x32_bf16(
            ak, bq[1][f], sacc[c][1], 0, 0, 0);
      }
    }
    __builtin_amdgcn_s_setprio(0);
  };

  auto smax = [&](f32x4 (&sacc)[4][2], int g, bool mask) {
#pragma unroll
    for (int c = 0; c < 4; ++c) {
      short4 pk;
#pragma unroll
      for (int reg = 0; reg < 4; ++reg) {
        int keyl = 16 * c + 4 * quad + reg;
        float p = (mask && keyl > rowl)
                      ? 0.f
                      : __builtin_amdgcn_exp2f(sacc[c][g][reg]);
        lsum[g] += p;
        ((short*)&pk)[reg] = f2bf(p);
      }
      *(short4*)&Ps[g][(2 * c + (quad >> 1)) * 512 + rowl * 8 + (quad & 1) * 4] =
          pk;
    }
  };

  auto pv2 = [&](int buf) {
    __asm__ volatile("s_waitcnt lgkmcnt(0)" ::: "memory");
    bf16x8 ap[2][2];
#pragma unroll
    for (int f = 0; f < 2; ++f) {
      ap[0][f] = *(const bf16x8*)&Ps[0][(4 * f + quad) * 512 + rowl * 8];
      ap[1][f] = *(const bf16x8*)&Ps[1][(4 * f + quad) * 512 + rowl * 8];
    }
    __builtin_amdgcn_s_setprio(1);
#pragma unroll
    for (int n = 0; n < 4; ++n) {
#pragma unroll
      for (int f = 0; f < 2; ++f) {
        bf16x8 bv =
            *(const bf16x8*)&Vs[buf][((4 * f + quad) * 64 + 16 * n + l16) * 8];
        oacc[n][0] = __builtin_amdgcn_mfma_f32_16x16x32_bf16(
            ap[0][f], bv, oacc[n][0], 0, 0, 0);
        oacc[n][1] = __builtin_amdgcn_mfma_f32_16x16x32_bf16(
            ap[1][f], bv, oacc[n][1], 0, 0, 0);
      }
    }
    __builtin_amdgcn_s_setprio(0);
  };

  for (int kt = 0; kt < NT - 2; ++kt) {
    const int buf = kt & 1;
    __syncthreads();
    stage_next(kt);
    f32x4 sacc[4][2] = {};
    qkt2(buf, sacc);
    smax(sacc, 0, false);
    smax(sacc, 1, false);
    pv2(buf);
  }
  {
    const int kt = NT - 2, buf = kt & 1;
    __syncthreads();
    stage_next(kt);
    f32x4 sacc[4][2] = {};
    qkt2(buf, sacc);
    smax(sacc, 0, true);
    smax(sacc, 1, false);
    pv2(buf);
  }
  {
    const int buf = (NT - 1) & 1;
    __syncthreads();
    f32x4 sacc1[4] = {};
    __builtin_amdgcn_s_setprio(1);
#pragma unroll
    for (int c = 0; c < 4; ++c)
#pragma unroll
      for (int f = 0; f < 2; ++f) {
        bf16x8 ak =
            *(const bf16x8*)&Ks[buf][((4 * f + quad) * 64 + 16 * c + l16) * 8];
        sacc1[c] = __builtin_amdgcn_mfma_f32_16x16x32_bf16(
            ak, bq[1][f], sacc1[c], 0, 0, 0);
      }
    __builtin_amdgcn_s_setprio(0);
#pragma unroll
    for (int c = 0; c < 4; ++c) {
      short4 pk;
#pragma unroll
      for (int reg = 0; reg < 4; ++reg) {
        int keyl = 16 * c + 4 * quad + reg;
        float p = (keyl > rowl) ? 0.f : __builtin_amdgcn_exp2f(sacc1[c][reg]);
        lsum[1] += p;
        ((short*)&pk)[reg] = f2bf(p);
      }
      *(short4*)&Ps[1][(2 * c + (quad >> 1)) * 512 + rowl * 8 + (quad & 1) * 4] =
          pk;
    }
    __asm__ volatile("s_waitcnt lgkmcnt(0)" ::: "memory");
    bf16x8 ap1[2];
#pragma unroll
    for (int f = 0; f < 2; ++f)
      ap1[f] = *(const bf16x8*)&Ps[1][(4 * f + quad) * 512 + rowl * 8];
    __builtin_amdgcn_s_setprio(1);
#pragma unroll
    for (int n = 0; n < 4; ++n)
#pragma unroll
      for (int f = 0; f < 2; ++f) {
        bf16x8 bv =
            *(const bf16x8*)&Vs[buf][((4 * f + quad) * 64 + 16 * n + l16) * 8];
        oacc[n][1] = __builtin_amdgcn_mfma_f32_16x16x32_bf16(
            ap1[f], bv, oacc[n][1], 0, 0, 0);
      }
    __builtin_amdgcn_s_setprio(0);
  }

#pragma unroll
  for (int g = 0; g < 2; ++g) {
    float ls = lsum[g];
    ls += __shfl_xor(ls, 16);
    ls += __shfl_xor(ls, 32);
    float linv[4];
#pragma unroll
    for (int reg = 0; reg < 4; ++reg)
      linv[reg] = 1.0f / __shfl(ls, 4 * quad + reg, 64);
#pragma unroll
    for (int reg = 0; reg < 4; ++reg) {
      const int row = (2 * pj + g) * 64 + 16 * wave + 4 * quad + reg;
      const int m = b * T_ + row;
      const int xv = (m >> 1) & 3;
#pragma unroll
      for (int n = 0; n < 4; ++n) {
        int c = h * 64 + 16 * n + l16;
        int cs = (c & ~31) | ((((c >> 3) & 3) ^ xv) << 3) | (c & 7);
        attb[(size_t)m * C_ + cs] = f2bf(oacc[n][g][reg] * linv[reg]);
      }
    }
  }
}

extern "C" void kernel_launch(void* const* d_in, const int* in_sizes, int n_in,
                              void* d_out, int out_size, void* d_ws, size_t ws_size,
                              hipStream_t stream) {
  const float* x      = (const float*)d_in[0];
  const float* w_qkv  = (const float*)d_in[1];
  const float* b_qkv  = (const float*)d_in[2];
  const float* w_proj = (const float*)d_in[3];
  const float* b_proj = (const float*)d_in[4];
  float* out = (float*)d_out;

  const size_t per = (size_t)B_ * H_ * T_ * D_;  // 4.19M
  short* Qp   = (short*)d_ws;
  short* Kp   = Qp + per;
  short* Vp   = Kp + per;
  short* attb = Vp + per;                   // [4096,1024] bf16 swizzled
  short* xb   = attb + per;                 // [4096,1024] bf16 swizzled
  short* wqt  = xb + per;                   // [3072,1024] bf16 swizzled
  short* wpt  = wqt + (size_t)3 * C_ * C_;  // [1024,1024] bf16 swizzled

  prep<<<1536, 256, 0, stream>>>(x, w_qkv, w_proj, xb, wqt, wpt);

  gemm_mfma<3 * C_, 128, true><<<dim3(768), 256, 0, stream>>>(
      xb, wqt, b_qkv, Qp, Kp, Vp, nullptr);

  attn_kernel<<<dim3(512), 256, 0, stream>>>(Qp, Kp, Vp, attb);

  gemm_mfma<C_, 64, false><<<dim3(512), 256, 0, stream>>>(
      attb, wpt, b_proj, nullptr, nullptr, nullptr, out);
}

// Round 4
// 176.022 us; speedup vs baseline: 1.0194x; 1.0156x over previous
//
#include <hip/hip_runtime.h>
#include <hip/hip_bf16.h>
#include <math.h>
#include <stdint.h>

#define B_ 2
#define T_ 2048
#define C_ 1024
#define H_ 16
#define D_ 64

typedef __attribute__((ext_vector_type(8))) short bf16x8;
typedef __attribute__((ext_vector_type(4))) float f32x4;

__device__ inline short f2bf(float f) {
  __hip_bfloat16 h = __float2bfloat16(f);
  return *(short*)&h;
}

// async global->LDS, 16B/lane. LDS image = wave-uniform base + lane*16.
__device__ inline void async16(const void* g, void* l) {
  __builtin_amdgcn_global_load_lds(
      (const __attribute__((address_space(1))) uint32_t*)g,
      (__attribute__((address_space(3))) uint32_t*)l, 16, 0, 0);
}

// ---------------------------------------------------------------------------
// Swizzle convention for GEMM operand images (A [M,1024] and B^T [N,1024]):
// chunk p of each 32-k group holds source chunk (p ^ ((row>>1)&3)).
// Fragment reads use chunk (quad ^ ((l16>>1)&3)) -> 2-way banks (free).
// ---------------------------------------------------------------------------

// One prep kernel: blocks [0,512) convert x -> bf16 swizzled (coalesced:
// each pass one full 4KB row per block); [512,1280) transpose w_qkv;
// [1280,1536) transpose w_proj.
__global__ __launch_bounds__(256) void prep(
    const float* __restrict__ X, const float* __restrict__ Wq,
    const float* __restrict__ Wp, short* __restrict__ Xb,
    short* __restrict__ Wqt, short* __restrict__ Wpt) {
  const int tid = threadIdx.x;
  const int blk = blockIdx.x;
  __shared__ short Ts[64][68];

  if (blk < 512) {  // convert_x: 8 rows per block, 1 row (1024 f32) per pass
    const int g = tid >> 3;        // 32-float group in row
    const int sub = tid & 7;       // 4-float slot in group
    const int sc = sub >> 1;       // source chunk 0..3
    const int e4 = (sub & 1) * 4;
#pragma unroll
    for (int pass = 0; pass < 8; ++pass) {
      const int m = blk * 8 + pass;
      float4 v = *(const float4*)(X + (size_t)m * C_ + tid * 4);
      const int xv = (m >> 1) & 3;
      short o[4] = {f2bf(v.x), f2bf(v.y), f2bf(v.z), f2bf(v.w)};
      *(uint2*)(Xb + (size_t)m * C_ + g * 32 + ((sc ^ xv) << 3) + e4) =
          *(uint2*)o;
    }
    return;
  }

  const float* W;
  short* Wt;
  int N, n0, k0;
  if (blk < 1280) {
    int i = blk - 512;
    W = Wq; Wt = Wqt; N = 3 * C_;
    n0 = (i % 48) * 64; k0 = (i / 48) * 64;
  } else {
    int i = blk - 1280;
    W = Wp; Wt = Wpt; N = C_;
    n0 = (i & 15) * 64; k0 = (i >> 4) * 64;
  }
  {
    int r = tid >> 2, c0 = (tid & 3) * 16;
    const float* src = W + (size_t)(k0 + r) * N + n0 + c0;
#pragma unroll
    for (int u = 0; u < 16; u += 4) {
      float4 v = *(const float4*)(src + u);
      Ts[r][c0 + u + 0] = f2bf(v.x);
      Ts[r][c0 + u + 1] = f2bf(v.y);
      Ts[r][c0 + u + 2] = f2bf(v.z);
      Ts[r][c0 + u + 3] = f2bf(v.w);
    }
  }
  __syncthreads();
  // write: 8 lanes cover one output row's 64 k (128 B contiguous, coalesced)
#pragma unroll
  for (int p = 0; p < 2; ++p) {
    int n = (tid >> 3) + p * 32;
    int kc = tid & 7;
    int xv = ((n0 + n) >> 1) & 3;
    int ka = kc * 8;
    int dk = (ka & ~31) | ((((ka >> 3) & 3) ^ xv) << 3);
    short tmp[8];
#pragma unroll
    for (int u = 0; u < 8; ++u) tmp[u] = Ts[ka + u][n];
    *(uint4*)(Wt + (size_t)(n0 + n) * 1024 + k0 + dk) = *(uint4*)tmp;
  }
}

// ---------------------------------------------------------------------------
// bf16 MFMA GEMM, 128xBN tile. Round 4: DEPTH-2 prefetch pipeline.
// 4 LDS buffers, BK=32 stages; iter t issues stage(t+2), then
// s_waitcnt vmcnt(2*LPS) (two stages' loads remain in flight -- never
// drained in the main loop), ONE raw s_barrier, ds_read+MFMA.
// Race-safety with one barrier: buf (t+2)%4's last readers ran in iter t-2,
// and every wave passed barrier(t-1) before any wave issues stage(t+2).
// QKV: BN=192 -> grid 32x16 = 512 blocks = exactly 2/CU (no tail);
//   LDS 4*(8+12)KB = 80KB -> 2 blocks/CU. 24 MFMA / 20KB staged per step.
// proj: BN=64 -> 4*(8+4)KB = 48KB -> 3 blocks/CU.
// XCD-rectangle block swizzle (round 3, kept): id%8 = xcd; each XCD gets a
// contiguous 8x8 rect of the 32x16 grid -> per-XCD operand panels L2-fit.
// QKV epilogue scatters to attention-tiled Q/K/V (Q pre-scaled by
// (1/sqrt(D))*log2(e) so attention uses raw exp2).
// ---------------------------------------------------------------------------
template <int N, int BN, bool QKV>
__global__ __launch_bounds__(256, 2) void gemm_mfma(
    const short* __restrict__ A, const short* __restrict__ Bt,
    const float* __restrict__ bias, short* __restrict__ Qp,
    short* __restrict__ Kp, short* __restrict__ Vp, float* __restrict__ Cout) {
  constexpr int NJ = BN / 32;      // n-tiles per wave (6 or 2)
  constexpr int BI = BN * 32;      // B image shorts per BK=32 stage
  constexpr int LPS = 2 + BN / 64; // async16 calls per stage (A:2 + B:BN/64)
  const int tid = threadIdx.x;
  const int wave = tid >> 6, lane = tid & 63;
  const int quad = lane >> 4, l16 = lane & 15;
  const int wm = wave >> 1, wn = wave & 1;

  // XCD-rectangle decode on the 32(by) x 16(bx) grid: 8 rects of 8x8.
  const int f = blockIdx.x;
  const int xcd = f & 7, r = f >> 3;
  const int lby = r >> 3, lbx = r & 7;
  const int by = (xcd >> 1) * 8 + lby;
  const int bx = (xcd & 1) * 8 + lbx;
  const int m0 = by * 128, n0 = bx * BN;

  __shared__ short As[4][4096];    // 128 rows x 32k, swizzled
  __shared__ short Bs[4][BI];      // BN rows x 32k, swizzled

  const int srow = tid >> 2, skc = tid & 3;
  const size_t arow0 = (size_t)(m0 + srow) * 1024 + skc * 8;
  const size_t brow0 = (size_t)(n0 + srow) * 1024 + skc * 8;

  f32x4 acc[4][NJ] = {};

  const int xi = quad ^ ((l16 >> 1) & 3);  // de-swizzle chunk select
  int aoff[4], boff[NJ];
#pragma unroll
  for (int i = 0; i < 4; ++i) aoff[i] = (wm * 64 + i * 16 + l16) * 32 + xi * 8;
#pragma unroll
  for (int j = 0; j < NJ; ++j)
    boff[j] = (wn * (BN / 2) + j * 16 + l16) * 32 + xi * 8;

  auto stage = [&](int t) {
    const int s = t & 3;
    const size_t kf = (size_t)t * 32;
    async16(A + arow0 + kf, &As[s][tid * 8]);
    async16(A + arow0 + (size_t)64 * 1024 + kf, &As[s][2048 + tid * 8]);
#pragma unroll
    for (int seg = 0; seg < BN / 64; ++seg)
      async16(Bt + brow0 + (size_t)(seg * 64) * 1024 + kf,
              &Bs[s][seg * 2048 + tid * 8]);
  };

  stage(0);
  stage(1);
  for (int t = 0; t < 32; ++t) {
    const int s = t & 3;
    if (t + 2 < 32) {
      stage(t + 2);
      // wait for stage t only; t+1 and t+2 (2*LPS loads) stay in flight
      if constexpr (BN == 192)
        __asm__ volatile("s_waitcnt vmcnt(10)" ::: "memory");
      else
        __asm__ volatile("s_waitcnt vmcnt(6)" ::: "memory");
    } else if (t + 1 < 32) {
      if constexpr (BN == 192)
        __asm__ volatile("s_waitcnt vmcnt(5)" ::: "memory");
      else
        __asm__ volatile("s_waitcnt vmcnt(3)" ::: "memory");
    } else {
      __asm__ volatile("s_waitcnt vmcnt(0)" ::: "memory");
    }
    __builtin_amdgcn_s_barrier();

    bf16x8 af[4], bfr[NJ];
#pragma unroll
    for (int i = 0; i < 4; ++i) af[i] = *(const bf16x8*)&As[s][aoff[i]];
#pragma unroll
    for (int j = 0; j < NJ; ++j) bfr[j] = *(const bf16x8*)&Bs[s][boff[j]];
#pragma unroll
    for (int i = 0; i < 4; ++i)
#pragma unroll
      for (int j = 0; j < NJ; ++j)
        acc[i][j] = __builtin_amdgcn_mfma_f32_16x16x32_bf16(
            af[i], bfr[j], acc[i][j], 0, 0, 0);
  }

  float bj[NJ];
#pragma unroll
  for (int j = 0; j < NJ; ++j) bj[j] = bias[n0 + wn * (BN / 2) + j * 16 + l16];

  if (QKV) {
#pragma unroll
    for (int i = 0; i < 4; ++i) {
#pragma unroll
      for (int reg = 0; reg < 4; ++reg) {
        int m = m0 + wm * 64 + i * 16 + quad * 4 + reg;
        int b = m >> 11, t = m & (T_ - 1);
#pragma unroll
        for (int j = 0; j < NJ; ++j) {
          int n = n0 + wn * (BN / 2) + j * 16 + l16;
          float v = acc[i][j][reg] + bj[j];
          int sel = n >> 10, cc = n & (C_ - 1);
          int hh = cc >> 6, d = cc & 63;
          size_t base = (size_t)(b * H_ + hh) * 131072 + (size_t)(t >> 6) * 4096;
          if (sel == 0) {
            // 0.125 * log2(e) = 0.18033688011
            Qp[base + (d >> 3) * 512 + (t & 63) * 8 + (d & 7)] =
                f2bf(v * 0.18033688011112042f);
          } else if (sel == 1) {
            Kp[base + (d >> 3) * 512 + (t & 63) * 8 + (d & 7)] = f2bf(v);
          } else {
            Vp[base + ((t & 63) >> 3) * 512 + d * 8 + (t & 7)] = f2bf(v);
          }
        }
      }
    }
  } else {
#pragma unroll
    for (int i = 0; i < 4; ++i) {
#pragma unroll
      for (int reg = 0; reg < 4; ++reg) {
        int m = m0 + wm * 64 + i * 16 + quad * 4 + reg;
#pragma unroll
        for (int j = 0; j < NJ; ++j) {
          int n = n0 + wn * (BN / 2) + j * 16 + l16;
          Cout[(size_t)m * N + n] = acc[i][j][reg] + bj[j];
        }
      }
    }
  }
}

// ---------------------------------------------------------------------------
// bf16 MFMA flash attention, S^T formulation, paired 64-query tiles
// (unchanged; verified rounds 2-3).
// ---------------------------------------------------------------------------
__global__ __launch_bounds__(256, 2) void attn_kernel(
    const short* __restrict__ Qt, const short* __restrict__ Kt,
    const short* __restrict__ Vt, short* __restrict__ attb) {
  const int tid = threadIdx.x;
  const int wave = tid >> 6, lane = tid & 63;
  const int quad = lane >> 4, l16 = lane & 15;

  const int blk = blockIdx.x;
  const int bh = blk & 31;
  const int i = blk >> 5;                       // 0..15
  const int pj = (i < 8) ? (15 - i) : (i - 8);  // pair index, heavy first
  const int NT = 2 * pj + 2;                    // key tiles for this pair
  const int h = bh & 15, b = bh >> 4;

  const short* Qg = Qt + (size_t)bh * 131072;
  const short* Kg = Kt + (size_t)bh * 131072;
  const short* Vg = Vt + (size_t)bh * 131072;

  __shared__ short Ks[2][4096];
  __shared__ short Vs[2][4096];
  __shared__ short Ps[2][4096];

  const int rowl = 16 * wave + l16;

  bf16x8 bq[2][2];
#pragma unroll
  for (int g = 0; g < 2; ++g)
#pragma unroll
    for (int f = 0; f < 2; ++f)
      bq[g][f] = *(const bf16x8*)(Qg +
                 (size_t)((2 * pj + g) * 8 + 4 * f + quad) * 512 + rowl * 8);

  async16(Kg + tid * 8, &Ks[0][tid * 8]);
  async16(Kg + 2048 + tid * 8, &Ks[0][2048 + tid * 8]);
  async16(Vg + tid * 8, &Vs[0][tid * 8]);
  async16(Vg + 2048 + tid * 8, &Vs[0][2048 + tid * 8]);

  f32x4 oacc[4][2] = {};
  float lsum[2] = {0.f, 0.f};

  auto stage_next = [&](int kt) {
    const int dst = (kt + 1) & 1;
    const short* kp = Kg + (size_t)(kt + 1) * 4096;
    const short* vp = Vg + (size_t)(kt + 1) * 4096;
    async16(kp + tid * 8, &Ks[dst][tid * 8]);
    async16(kp + 2048 + tid * 8, &Ks[dst][2048 + tid * 8]);
    async16(vp + tid * 8, &Vs[dst][tid * 8]);
    async16(vp + 2048 + tid * 8, &Vs[dst][2048 + tid * 8]);
  };

  auto qkt2 = [&](int buf, f32x4 (&sacc)[4][2]) {
    __builtin_amdgcn_s_setprio(1);
#pragma unroll
    for (int c = 0; c < 4; ++c) {
#pragma unroll
      for (int f = 0; f < 2; ++f) {
        bf16x8 ak =
            *(const bf16x8*)&Ks[buf][((4 * f + quad) * 64 + 16 * c + l16) * 8];
        sacc[c][0] = __builtin_amdgcn_mfma_f32_16x16x32_bf16(
            ak, bq[0][f], sacc[c][0], 0, 0, 0);
        sacc[c][1] = __builtin_amdgcn_mfma_f32_16x16x32_bf16(
            ak, bq[1][f], sacc[c][1], 0, 0, 0);
      }
    }
    __builtin_amdgcn_s_setprio(0);
  };

  auto smax = [&](f32x4 (&sacc)[4][2], int g, bool mask) {
#pragma unroll
    for (int c = 0; c < 4; ++c) {
      short4 pk;
#pragma unroll
      for (int reg = 0; reg < 4; ++reg) {
        int keyl = 16 * c + 4 * quad + reg;
        float p = (mask && keyl > rowl)
                      ? 0.f
                      : __builtin_amdgcn_exp2f(sacc[c][g][reg]);
        lsum[g] += p;
        ((short*)&pk)[reg] = f2bf(p);
      }
      *(short4*)&Ps[g][(2 * c + (quad >> 1)) * 512 + rowl * 8 + (quad & 1) * 4] =
          pk;
    }
  };

  auto pv2 = [&](int buf) {
    __asm__ volatile("s_waitcnt lgkmcnt(0)" ::: "memory");
    bf16x8 ap[2][2];
#pragma unroll
    for (int f = 0; f < 2; ++f) {
      ap[0][f] = *(const bf16x8*)&Ps[0][(4 * f + quad) * 512 + rowl * 8];
      ap[1][f] = *(const bf16x8*)&Ps[1][(4 * f + quad) * 512 + rowl * 8];
    }
    __builtin_amdgcn_s_setprio(1);
#pragma unroll
    for (int n = 0; n < 4; ++n) {
#pragma unroll
      for (int f = 0; f < 2; ++f) {
        bf16x8 bv =
            *(const bf16x8*)&Vs[buf][((4 * f + quad) * 64 + 16 * n + l16) * 8];
        oacc[n][0] = __builtin_amdgcn_mfma_f32_16x16x32_bf16(
            ap[0][f], bv, oacc[n][0], 0, 0, 0);
        oacc[n][1] = __builtin_amdgcn_mfma_f32_16x16x32_bf16(
            ap[1][f], bv, oacc[n][1], 0, 0, 0);
      }
    }
    __builtin_amdgcn_s_setprio(0);
  };

  for (int kt = 0; kt < NT - 2; ++kt) {
    const int buf = kt & 1;
    __syncthreads();
    stage_next(kt);
    f32x4 sacc[4][2] = {};
    qkt2(buf, sacc);
    smax(sacc, 0, false);
    smax(sacc, 1, false);
    pv2(buf);
  }
  {
    const int kt = NT - 2, buf = kt & 1;
    __syncthreads();
    stage_next(kt);
    f32x4 sacc[4][2] = {};
    qkt2(buf, sacc);
    smax(sacc, 0, true);
    smax(sacc, 1, false);
    pv2(buf);
  }
  {
    const int buf = (NT - 1) & 1;
    __syncthreads();
    f32x4 sacc1[4] = {};
    __builtin_amdgcn_s_setprio(1);
#pragma unroll
    for (int c = 0; c < 4; ++c)
#pragma unroll
      for (int f = 0; f < 2; ++f) {
        bf16x8 ak =
            *(const bf16x8*)&Ks[buf][((4 * f + quad) * 64 + 16 * c + l16) * 8];
        sacc1[c] = __builtin_amdgcn_mfma_f32_16x16x32_bf16(
            ak, bq[1][f], sacc1[c], 0, 0, 0);
      }
    __builtin_amdgcn_s_setprio(0);
#pragma unroll
    for (int c = 0; c < 4; ++c) {
      short4 pk;
#pragma unroll
      for (int reg = 0; reg < 4; ++reg) {
        int keyl = 16 * c + 4 * quad + reg;
        float p = (keyl > rowl) ? 0.f : __builtin_amdgcn_exp2f(sacc1[c][reg]);
        lsum[1] += p;
        ((short*)&pk)[reg] = f2bf(p);
      }
      *(short4*)&Ps[1][(2 * c + (quad >> 1)) * 512 + rowl * 8 + (quad & 1) * 4] =
          pk;
    }
    __asm__ volatile("s_waitcnt lgkmcnt(0)" ::: "memory");
    bf16x8 ap1[2];
#pragma unroll
    for (int f = 0; f < 2; ++f)
      ap1[f] = *(const bf16x8*)&Ps[1][(4 * f + quad) * 512 + rowl * 8];
    __builtin_amdgcn_s_setprio(1);
#pragma unroll
    for (int n = 0; n < 4; ++n)
#pragma unroll
      for (int f = 0; f < 2; ++f) {
        bf16x8 bv =
            *(const bf16x8*)&Vs[buf][((4 * f + quad) * 64 + 16 * n + l16) * 8];
        oacc[n][1] = __builtin_amdgcn_mfma_f32_16x16x32_bf16(
            ap1[f], bv, oacc[n][1], 0, 0, 0);
      }
    __builtin_amdgcn_s_setprio(0);
  }

#pragma unroll
  for (int g = 0; g < 2; ++g) {
    float ls = lsum[g];
    ls += __shfl_xor(ls, 16);
    ls += __shfl_xor(ls, 32);
    float linv[4];
#pragma unroll
    for (int reg = 0; reg < 4; ++reg)
      linv[reg] = 1.0f / __shfl(ls, 4 * quad + reg, 64);
#pragma unroll
    for (int reg = 0; reg < 4; ++reg) {
      const int row = (2 * pj + g) * 64 + 16 * wave + 4 * quad + reg;
      const int m = b * T_ + row;
      const int xv = (m >> 1) & 3;
#pragma unroll
      for (int n = 0; n < 4; ++n) {
        int c = h * 64 + 16 * n + l16;
        int cs = (c & ~31) | ((((c >> 3) & 3) ^ xv) << 3) | (c & 7);
        attb[(size_t)m * C_ + cs] = f2bf(oacc[n][g][reg] * linv[reg]);
      }
    }
  }
}

extern "C" void kernel_launch(void* const* d_in, const int* in_sizes, int n_in,
                              void* d_out, int out_size, void* d_ws, size_t ws_size,
                              hipStream_t stream) {
  const float* x      = (const float*)d_in[0];
  const float* w_qkv  = (const float*)d_in[1];
  const float* b_qkv  = (const float*)d_in[2];
  const float* w_proj = (const float*)d_in[3];
  const float* b_proj = (const float*)d_in[4];
  float* out = (float*)d_out;

  const size_t per = (size_t)B_ * H_ * T_ * D_;  // 4.19M
  short* Qp   = (short*)d_ws;
  short* Kp   = Qp + per;
  short* Vp   = Kp + per;
  short* attb = Vp + per;                   // [4096,1024] bf16 swizzled
  short* xb   = attb + per;                 // [4096,1024] bf16 swizzled
  short* wqt  = xb + per;                   // [3072,1024] bf16 swizzled
  short* wpt  = wqt + (size_t)3 * C_ * C_;  // [1024,1024] bf16 swizzled

  prep<<<1536, 256, 0, stream>>>(x, w_qkv, w_proj, xb, wqt, wpt);

  gemm_mfma<3 * C_, 192, true><<<dim3(512), 256, 0, stream>>>(
      xb, wqt, b_qkv, Qp, Kp, Vp, nullptr);

  attn_kernel<<<dim3(512), 256, 0, stream>>>(Qp, Kp, Vp, attb);

  gemm_mfma<C_, 64, false><<<dim3(512), 256, 0, stream>>>(
      attb, wpt, b_proj, nullptr, nullptr, nullptr, out);
}